// Round 21
// baseline (262.408 us; speedup 1.0000x reference)
//
#include <hip/hip_runtime.h>
#include <hip/hip_bf16.h>

typedef short bf16x8 __attribute__((ext_vector_type(8)));
typedef float f32x4 __attribute__((ext_vector_type(4)));
typedef unsigned short u16x8 __attribute__((ext_vector_type(8)));

#define MFMA16(a,b,c) __builtin_amdgcn_mfma_f32_16x16x32_bf16((a),(b),(c),0,0,0)

__device__ inline unsigned short f32_to_bf16(float f){
  union { float f; unsigned u; } v; v.f = f;
  unsigned u = v.u;
  u += 0x7FFFu + ((u >> 16) & 1u);
  return (unsigned short)(u >> 16);
}
__device__ inline float bf16_to_f32(unsigned short u){
  union { unsigned u; float f; } v; v.u = ((unsigned)u)<<16; return v.f;
}

// gelu tanh-approx via sigmoid identity: ~6 VALU ops.
__device__ inline float gelu_fast(float x){
  const float c1 = -2.302118484f;      // -2*log2(e)*0.7978845608
  const float c2 = -0.102944227f;      // c1*0.044715
  float p = __builtin_amdgcn_exp2f(x*__builtin_fmaf(c2, x*x, c1));
  return x*__builtin_amdgcn_rcpf(1.0f + p);
}

__device__ inline void gload16(const void* g, void* l){
  __builtin_amdgcn_global_load_lds(
      (const __attribute__((address_space(1))) void*)g,
      (__attribute__((address_space(3))) void*)l, 16, 0, 0);
}

// XCD-chunked bijective swizzle (requires nwg % 8 == 0)
__device__ inline int xcd_swz(int lin, int nwg){
  int cpx = nwg >> 3;
  return (lin & 7)*cpx + (lin >> 3);
}

// ---------------- mask dtype detection -------------------------------------
__global__ void detect_mask_kernel(const unsigned* __restrict__ m, int* __restrict__ flag){
  __shared__ int s;
  if (threadIdx.x == 0) s = 0;
  __syncthreads();
  unsigned w = m[threadIdx.x];
  if (w > 1u) atomicOr(&s, 1);
  __syncthreads();
  if (threadIdx.x == 0) *flag = s;   // 1 => byte/bool storage, 0 => int32
}

// mask -> bf16 additive bias in fragment order: biasr[qgrp][jt][lane][16elems]
__global__ __launch_bounds__(256) void mask_bias_kernel(
    const void* __restrict__ mask, const int* __restrict__ flag,
    unsigned short* __restrict__ biasr){
  __shared__ float mt[16][64];
  int qg = blockIdx.x, jt = blockIdx.y;   // qg in [0,64)
  int t = threadIdx.x;
  int fl = *flag;
  int jc = jt*64 + (t&63);
  #pragma unroll
  for (int k2=0;k2<4;k2++){
    int qr = qg*16 + (t>>6) + k2*4;       // qr in [0,1024)
    bool a = fl ? (((const unsigned char*)mask)[(size_t)qr*1024 + jc] != 0)
                : (((const int*)mask)[(size_t)qr*1024 + jc] != 0);
    mt[(t>>6)+k2*4][t&63] = a ? -23.083120654223414f : -1e30f;
  }
  __syncthreads();
  ushort4 ob;
  unsigned short tmp[4];
  #pragma unroll
  for (int u=0;u<4;u++){
    int p = t*4+u;
    int e = p&15, lane = p>>4;
    int i = e>>2, jj = e&3;
    int ln2 = lane&15, g2 = lane>>4;
    tmp[u] = f32_to_bf16(mt[g2*4+i][jj*16+ln2]);
  }
  ob.x=tmp[0]; ob.y=tmp[1]; ob.z=tmp[2]; ob.w=tmp[3];
  *(ushort4*)&biasr[((size_t)(qg*16+jt)*64)*16 + t*4] = ob;
}

// ---------------- weight convert + transpose (float4 vectorized) ------------
__global__ __launch_bounds__(256) void transpose_cvt_kernel(
    const float* __restrict__ W, unsigned short* __restrict__ WT, int K, int N){
  __shared__ float tile[32][37];
  int n0 = blockIdx.x*32, k0 = blockIdx.y*32;
  int r = threadIdx.x>>3, c4 = threadIdx.x&7;
  float4 v = *(const float4*)&W[(size_t)(k0+r)*N + n0 + c4*4];
  tile[r][c4*4+0]=v.x; tile[r][c4*4+1]=v.y; tile[r][c4*4+2]=v.z; tile[r][c4*4+3]=v.w;
  __syncthreads();
  ushort4 o;
  o.x = f32_to_bf16(tile[c4*4+0][r]);
  o.y = f32_to_bf16(tile[c4*4+1][r]);
  o.z = f32_to_bf16(tile[c4*4+2][r]);
  o.w = f32_to_bf16(tile[c4*4+3][r]);
  *(ushort4*)&WT[(size_t)(n0+r)*K + k0 + c4*4] = o;
}

// V slice of qkv [4096][3072] -> VT [b][1024 d][1024 n] bf16
__global__ __launch_bounds__(256) void vtrans_kernel(
    const unsigned short* __restrict__ qkv, unsigned short* __restrict__ vt){
  __shared__ unsigned short t[32][33];
  int b = blockIdx.z;
  int n0 = blockIdx.x*32, d0 = blockIdx.y*32;
  int tx = threadIdx.x & 31, ty = threadIdx.x >> 5;
  #pragma unroll
  for (int r=0;r<4;r++)
    t[ty+8*r][tx] = qkv[(size_t)(b*1024 + n0+ty+8*r)*3072 + 2048 + d0+tx];
  __syncthreads();
  #pragma unroll
  for (int r=0;r<4;r++)
    vt[((size_t)b<<20) + (size_t)(d0+ty+8*r)*1024 + n0+tx] = t[tx][ty+8*r];
}

__global__ void bias_concat_kernel(const float* __restrict__ bq,
                                   const float* __restrict__ bkv,
                                   float* __restrict__ dst){
  int i = blockIdx.x*256 + threadIdx.x;
  if (i < 3072) dst[i] = (i < 1024) ? bq[i] : bkv[i-1024];
}

// ---------------- layernorm (row = 1024 floats) -----------------------------
__global__ __launch_bounds__(256) void ln_kernel(const float* __restrict__ x,
                                                 unsigned short* __restrict__ xn){
  const int C = 1024;
  size_t row = blockIdx.x;
  float4 v = reinterpret_cast<const float4*>(x + row*C)[threadIdx.x];
  float s = v.x+v.y+v.z+v.w;
  float q = v.x*v.x+v.y*v.y+v.z*v.z+v.w*v.w;
  #pragma unroll
  for (int off=32; off; off>>=1){ s += __shfl_xor(s,off); q += __shfl_xor(q,off); }
  __shared__ float sm[8];
  int wv = threadIdx.x>>6, ln = threadIdx.x&63;
  if (ln==0){ sm[wv]=s; sm[4+wv]=q; }
  __syncthreads();
  float S = sm[0]+sm[1]+sm[2]+sm[3];
  float Q = sm[4]+sm[5]+sm[6]+sm[7];
  float mu  = S*(1.0f/1024.0f);
  float var = Q*(1.0f/1024.0f) - mu*mu;
  float inv = rsqrtf(var + 1e-6f);
  ushort4 o;
  o.x = f32_to_bf16((v.x-mu)*inv);
  o.y = f32_to_bf16((v.y-mu)*inv);
  o.z = f32_to_bf16((v.z-mu)*inv);
  o.w = f32_to_bf16((v.w-mu)*inv);
  reinterpret_cast<ushort4*>(xn + row*C)[threadIdx.x] = o;
}

// ---------------- 128x128 4-wave GEMM, templated BK (32 or 64) --------------
template<int EPI, int BK>
__global__ __launch_bounds__(256) void gemm128_kernel(
    const unsigned short* __restrict__ A,
    const unsigned short* __restrict__ BT,
    const float* __restrict__ bias,
    const float* __restrict__ resid,
    void* __restrict__ Cout,
    int M, int N, int K)
{
  constexpr int CPR = BK/8;            // 16B chunks per row
  constexpr int PT  = BK/16;           // staged chunks per thread per operand
  constexpr int TS  = 128*BK;          // shorts per operand tile
  __shared__ __align__(16) unsigned short lds[3][2*TS];
  int tid = threadIdx.x, wave = tid>>6, lane = tid&63;
  int nbx = gridDim.x;
  int lin = blockIdx.y*nbx + blockIdx.x;
  int w = xcd_swz(lin, nbx*gridDim.y);
  int m0 = (w/nbx)*128, n0 = (w%nbx)*128;
  int ln = lane&15, g = lane>>4;
  int wm = wave>>1, wn = wave&1;

  const unsigned short* sA[PT];
  const unsigned short* sB[PT];
  #pragma unroll
  for (int p=0;p<PT;p++){
    int idx = p*256 + tid;
    int row = idx/CPR, c = idx%CPR;
    int ch = (BK==32) ? (c ^ ((row>>1)&3)) : (c ^ (row&7));
    sA[p] = A  + (size_t)(m0+row)*K + ch*8;
    sB[p] = BT + (size_t)(n0+row)*K + ch*8;
  }

  f32x4 acc[4][4] = {};
  int nt = K/BK;

  auto STAGE = [&](int t, int buf){
    int ko = t*BK;
    #pragma unroll
    for (int p=0;p<PT;p++)
      gload16(sA[p]+ko, (char*)&lds[buf][0]  + (p*256 + wave*64)*16);
    #pragma unroll
    for (int p=0;p<PT;p++)
      gload16(sB[p]+ko, (char*)&lds[buf][TS] + (p*256 + wave*64)*16);
  };

  STAGE(0,0); STAGE(1,1); STAGE(2,2);

  int cb = 0;
  for (int t=0; t<nt; ++t){
    int rem = nt-1-t;
    if (BK==32){
      if (rem >= 2)      asm volatile("s_waitcnt vmcnt(8)" ::: "memory");
      else if (rem == 1) asm volatile("s_waitcnt vmcnt(4)" ::: "memory");
      else               asm volatile("s_waitcnt vmcnt(0)" ::: "memory");
    } else {
      if (rem >= 2)      asm volatile("s_waitcnt vmcnt(16)" ::: "memory");
      else if (rem == 1) asm volatile("s_waitcnt vmcnt(8)" ::: "memory");
      else               asm volatile("s_waitcnt vmcnt(0)" ::: "memory");
    }
    __builtin_amdgcn_s_barrier();

    const unsigned short* lb = lds[cb];
    #pragma unroll
    for (int kk=0; kk<BK/32; ++kk){
      int swz = (BK==32) ? (g ^ ((ln>>1)&3)) : ((kk*4+g) ^ (ln&7));
      bf16x8 a[4], b[4];
      #pragma unroll
      for (int mi=0;mi<4;mi++)
        a[mi] = *(const bf16x8*)(lb + (wm*64+mi*16+ln)*BK + swz*8);
      #pragma unroll
      for (int ni=0;ni<4;ni++)
        b[ni] = *(const bf16x8*)(lb + TS + (wn*64+ni*16+ln)*BK + swz*8);
      #pragma unroll
      for (int mi=0;mi<4;mi++)
        #pragma unroll
        for (int ni=0;ni<4;ni++)
          acc[mi][ni] = MFMA16(a[mi], b[ni], acc[mi][ni]);
    }

    asm volatile("s_waitcnt lgkmcnt(0)" ::: "memory");
    __builtin_amdgcn_s_barrier();
    if (t+3 < nt) STAGE(t+3, cb);
    cb = (cb==2) ? 0 : cb+1;
  }

  #pragma unroll
  for (int mi=0;mi<4;mi++){
    int r0 = m0 + wm*64 + mi*16 + g*4;
    #pragma unroll
    for (int ni=0;ni<4;ni++){
      int c = n0 + wn*64 + ni*16 + ln;
      float bs = bias[c];
      f32x4 cc = acc[mi][ni];
      #pragma unroll
      for (int i=0;i<4;i++){
        int r = r0 + i;
        float v = cc[i] + bs;
        if (EPI == 1){
          v += resid[(size_t)r*N + c];
          ((float*)Cout)[(size_t)r*N + c] = v;
        } else if (EPI == 2){
          ((unsigned short*)Cout)[(size_t)r*N + c] = f32_to_bf16(gelu_fast(v));
        } else {
          ((unsigned short*)Cout)[(size_t)r*N + c] = f32_to_bf16(v);
        }
      }
    }
  }
}

// ---------------- fused attention: QBLK=128 (4 waves x 32 q-rows) -----------
// K/V staged once per 128 q rows (staging bytes halved vs QBLK=64); each wave
// runs 2 sequential 16-row groups, amortizing the staging stall over 2x MFMA.
__global__ __launch_bounds__(256,6) void attn_kernel(
    const unsigned short* __restrict__ qkv,
    const unsigned short* __restrict__ vt,
    const unsigned short* __restrict__ biasr,
    unsigned short* __restrict__ pn,
    float* __restrict__ lsumg)
{
  const int N = 1024, NK = 3072;
  const float SCL = 0.18033688011112042f;   // 0.125 * log2(e)
  __shared__ __align__(16) unsigned short lK[64*64];
  __shared__ __align__(16) unsigned short lV[64*64];
  __shared__ __align__(16) unsigned short plds[4][16][72];
  int bh = blockIdx.x, qt = blockIdx.y, sp = blockIdx.z;
  int b = bh>>4, h = bh&15;
  int tid = threadIdx.x, wave = tid>>6, lane = tid&63;
  int ln = lane&15, g = lane>>4;
  size_t base = (size_t)b*N;
  int q_local = qt*128 + wave*32;

  bf16x8 aq0[2], aq1[2];
  #pragma unroll
  for (int qq=0;qq<2;qq++){
    const unsigned short* qp = qkv + (base + q_local + qq*16 + ln)*NK + h*64;
    aq0[qq] = *(const bf16x8*)(qp + g*8);
    aq1[qq] = *(const bf16x8*)(qp + 32 + g*8);
  }

  int r0s = tid>>3,        c0 = (tid&7) ^ (r0s&7);
  int r1s = 32 + (tid>>3), c1 = (tid&7) ^ (r1s&7);
  const unsigned short* kg0 = qkv + (base + r0s)*NK + 1024 + h*64 + c0*8;
  const unsigned short* kg1 = qkv + (base + r1s)*NK + 1024 + h*64 + c1*8;
  const unsigned short* vg0 = vt + ((size_t)b<<20) + (size_t)(h*64 + r0s)*N + c0*8;
  const unsigned short* vg1 = vt + ((size_t)b<<20) + (size_t)(h*64 + r1s)*N + c1*8;
  char* lKd0 = (char*)lK + (wave*64)*16;
  char* lKd1 = (char*)lK + (256 + wave*64)*16;
  char* lVd0 = (char*)lV + (wave*64)*16;
  char* lVd1 = (char*)lV + (256 + wave*64)*16;

  // qgrp = q_local/16 = qt*8 + wave*2 + qq
  const unsigned short* brp = biasr +
      (((size_t)(qt*8 + wave*2)*16)*64 + lane)*16;

  f32x4 oacc[2][4] = {};
  float lsum[2][4] = {};
  const int xl = (ln&7);

  for (int t=0; t<8; ++t){
    int j0 = sp*512 + t*64;
    __syncthreads();
    gload16(kg0 + (size_t)j0*NK, lKd0);
    gload16(kg1 + (size_t)j0*NK, lKd1);
    gload16(vg0 + j0, lVd0);
    gload16(vg1 + j0, lVd1);
    int jt = j0>>6;
    asm volatile("s_waitcnt vmcnt(0)" ::: "memory");
    __builtin_amdgcn_s_barrier();

    #pragma unroll
    for (int qq=0;qq<2;qq++){
      bf16x8 bb0 = *(const bf16x8*)(brp + (size_t)qq*16384 + (size_t)jt*1024);
      bf16x8 bb1 = *(const bf16x8*)(brp + (size_t)qq*16384 + (size_t)jt*1024 + 8);
      f32x4 s[4];
      #pragma unroll
      for (int jj=0;jj<4;jj++){
        int row = jj*16+ln;
        bf16x8 k0 = *(const bf16x8*)((const char*)lK + row*128 + ((g^xl)<<4));
        bf16x8 k1 = *(const bf16x8*)((const char*)lK + row*128 + (((g+4)^xl)<<4));
        s[jj] = (f32x4){};
        s[jj] = MFMA16(aq0[qq], k0, s[jj]);
        s[jj] = MFMA16(aq1[qq], k1, s[jj]);
      }
      #pragma unroll
      for (int i=0;i<4;i++){
        #pragma unroll
        for (int jj=0;jj<4;jj++){
          int e = i*4+jj;
          unsigned short bu = (e<8) ? (unsigned short)bb0[e] : (unsigned short)bb1[e-8];
          float ev = exp2f(fmaf(s[jj][i], SCL, bf16_to_f32(bu)));
          lsum[qq][i] += ev;
          plds[wave][4*g+i][jj*16+ln] = f32_to_bf16(ev);
        }
      }
      asm volatile("s_waitcnt lgkmcnt(0)" ::: "memory");
      __builtin_amdgcn_sched_barrier(0);
      bf16x8 p0 = *(const bf16x8*)&plds[wave][ln][g*8];
      bf16x8 p1 = *(const bf16x8*)&plds[wave][ln][32 + g*8];
      #pragma unroll
      for (int nd=0;nd<4;nd++){
        int row = nd*16+ln;
        bf16x8 v0 = *(const bf16x8*)((const char*)lV + row*128 + ((g^xl)<<4));
        bf16x8 v1 = *(const bf16x8*)((const char*)lV + row*128 + (((g+4)^xl)<<4));
        oacc[qq][nd] = MFMA16(p0, v0, oacc[qq][nd]);
        oacc[qq][nd] = MFMA16(p1, v1, oacc[qq][nd]);
      }
      // ensure this group's plds/v reads retired before next group's writes
      asm volatile("s_waitcnt lgkmcnt(0)" ::: "memory");
      __builtin_amdgcn_sched_barrier(0);
    }
  }

  #pragma unroll
  for (int qq=0;qq<2;qq++){
    #pragma unroll
    for (int i=0;i<4;i++){
      float l = lsum[qq][i];
      l += __shfl_xor(l,1); l += __shfl_xor(l,2);
      l += __shfl_xor(l,4); l += __shfl_xor(l,8);
      if (ln == 0)
        lsumg[((size_t)sp<<16) + (size_t)(base + q_local + qq*16 + 4*g + i)*16 + h] = l;
    }
    #pragma unroll
    for (int nd=0;nd<4;nd++){
      #pragma unroll
      for (int i=0;i<4;i++){
        int qr = q_local + qq*16 + 4*g + i;
        pn[((size_t)sp<<22) + (base+qr)*1024 + h*64 + nd*16 + ln] =
            f32_to_bf16(oacc[qq][nd][i]);
      }
    }
  }
}

// combine: o = (pn0+pn1)/(l0+l1), bf16 out.
__global__ __launch_bounds__(256) void attn_reduce_kernel(
    const unsigned short* __restrict__ pn,
    const float* __restrict__ lsumg,
    unsigned short* __restrict__ o)
{
  size_t idx = ((size_t)blockIdx.x*256 + threadIdx.x)*8;
  int r = (int)(idx>>10);
  int h = (int)((idx&1023)>>6);
  float inv = 1.0f/(lsumg[(size_t)r*16+h] + lsumg[(1u<<16) + (size_t)r*16+h]);
  u16x8 p0 = *(const u16x8*)(pn + idx);
  u16x8 p1 = *(const u16x8*)(pn + (1u<<22) + idx);
  u16x8 res;
  #pragma unroll
  for (int e=0;e<8;e++)
    res[e] = f32_to_bf16((bf16_to_f32((unsigned short)p0[e]) +
                          bf16_to_f32((unsigned short)p1[e]))*inv);
  *(u16x8*)(o + idx) = res;
}

// ---------------- host ------------------------------------------------------
extern "C" void kernel_launch(void* const* d_in, const int* in_sizes, int n_in,
                              void* d_out, int out_size, void* d_ws, size_t ws_size,
                              hipStream_t stream)
{
  (void)in_sizes; (void)n_in; (void)out_size; (void)ws_size;
  const float* x   = (const float*)d_in[0];
  const void*  mask= d_in[1];
  const float* wq  = (const float*)d_in[2];
  const float* bq  = (const float*)d_in[3];
  const float* wkv = (const float*)d_in[4];
  const float* bkv = (const float*)d_in[5];
  const float* wo  = (const float*)d_in[6];
  const float* bo  = (const float*)d_in[7];
  const float* w1  = (const float*)d_in[8];
  const float* b1  = (const float*)d_in[9];
  const float* w2  = (const float*)d_in[10];
  const float* b2  = (const float*)d_in[11];
  float* out = (float*)d_out;

  char* ws = (char*)d_ws;
  size_t off = 0;
  auto alloc = [&](size_t bytes){ size_t o = off; off += (bytes + 255) & ~(size_t)255; return o; };
  unsigned short* WqkvT = (unsigned short*)(ws + alloc(3072u*1024u*2));
  unsigned short* WoT   = (unsigned short*)(ws + alloc(1024u*1024u*2));
  unsigned short* W1T   = (unsigned short*)(ws + alloc(4096u*1024u*2));
  unsigned short* W2T   = (unsigned short*)(ws + alloc(1024u*4096u*2));
  float*          BIASQ = (float*)(ws + alloc(3072u*4));
  int*            FLAG  = (int*)(ws + alloc(256));
  float*          LSUM  = (float*)(ws + alloc(2u*4096u*16u*4));
  unsigned short* BIASR = (unsigned short*)(ws + alloc(64u*16u*64u*16u*2)); // 2MB
  unsigned short* XN    = (unsigned short*)(ws + alloc(4096u*1024u*2));
  float*          X1    = (float*)(ws + alloc(4096u*1024u*4));  // PN aliases
  unsigned short* QKV   = (unsigned short*)(ws + alloc(4096u*4096u*2));
  unsigned short* VT    = QKV + (size_t)4096u*3072u;
  unsigned short* PN    = (unsigned short*)X1;

  // prep
  transpose_cvt_kernel<<<dim3(32,32),  256, 0, stream>>>(wq,  WqkvT,               1024, 1024);
  transpose_cvt_kernel<<<dim3(64,32),  256, 0, stream>>>(wkv, WqkvT + 1024u*1024u, 1024, 2048);
  transpose_cvt_kernel<<<dim3(32,32),  256, 0, stream>>>(wo,  WoT,                 1024, 1024);
  transpose_cvt_kernel<<<dim3(128,32), 256, 0, stream>>>(w1,  W1T,                 1024, 4096);
  transpose_cvt_kernel<<<dim3(32,128), 256, 0, stream>>>(w2,  W2T,                 4096, 1024);
  bias_concat_kernel<<<12, 256, 0, stream>>>(bq, bkv, BIASQ);
  detect_mask_kernel<<<1, 256, 0, stream>>>((const unsigned*)mask, FLAG);
  mask_bias_kernel<<<dim3(64,16), 256, 0, stream>>>(mask, FLAG, BIASR);

  // block
  ln_kernel<<<4096, 256, 0, stream>>>(x, XN);
  gemm128_kernel<0,32><<<dim3(24,32), 256, 0, stream>>>(XN, WqkvT, BIASQ, nullptr, QKV, 4096, 3072, 1024);
  vtrans_kernel<<<dim3(32,32,4), 256, 0, stream>>>(QKV, VT);
  attn_kernel<<<dim3(64,8,2), 256, 0, stream>>>(QKV, VT, BIASR, PN, LSUM);
  attn_reduce_kernel<<<2048, 256, 0, stream>>>(PN, LSUM, XN);
  gemm128_kernel<1,64><<<dim3(8,32), 256, 0, stream>>>(XN, WoT, bo, x, X1, 4096, 1024, 1024);
  ln_kernel<<<4096, 256, 0, stream>>>(X1, XN);
  gemm128_kernel<2,32><<<dim3(32,32), 256, 0, stream>>>(XN, W1T, b1, nullptr, QKV, 4096, 4096, 1024);
  gemm128_kernel<1,64><<<dim3(8,32), 256, 0, stream>>>(QKV, W2T, b2, X1, out, 4096, 1024, 4096);
}

// Round 22
// 236.007 us; speedup vs baseline: 1.1119x; 1.1119x over previous
//
#include <hip/hip_runtime.h>
#include <hip/hip_bf16.h>

typedef short bf16x8 __attribute__((ext_vector_type(8)));
typedef float f32x4 __attribute__((ext_vector_type(4)));
typedef unsigned short u16x8 __attribute__((ext_vector_type(8)));

#define MFMA16(a,b,c) __builtin_amdgcn_mfma_f32_16x16x32_bf16((a),(b),(c),0,0,0)

__device__ inline unsigned short f32_to_bf16(float f){
  union { float f; unsigned u; } v; v.f = f;
  unsigned u = v.u;
  u += 0x7FFFu + ((u >> 16) & 1u);
  return (unsigned short)(u >> 16);
}
__device__ inline float bf16_to_f32(unsigned short u){
  union { unsigned u; float f; } v; v.u = ((unsigned)u)<<16; return v.f;
}

// gelu tanh-approx via sigmoid identity: ~6 VALU ops.
__device__ inline float gelu_fast(float x){
  const float c1 = -2.302118484f;      // -2*log2(e)*0.7978845608
  const float c2 = -0.102944227f;      // c1*0.044715
  float p = __builtin_amdgcn_exp2f(x*__builtin_fmaf(c2, x*x, c1));
  return x*__builtin_amdgcn_rcpf(1.0f + p);
}

__device__ inline void gload16(const void* g, void* l){
  __builtin_amdgcn_global_load_lds(
      (const __attribute__((address_space(1))) void*)g,
      (__attribute__((address_space(3))) void*)l, 16, 0, 0);
}

// XCD-chunked bijective swizzle (requires nwg % 8 == 0)
__device__ inline int xcd_swz(int lin, int nwg){
  int cpx = nwg >> 3;
  return (lin & 7)*cpx + (lin >> 3);
}

// ---------------- mask dtype detection -------------------------------------
__global__ void detect_mask_kernel(const unsigned* __restrict__ m, int* __restrict__ flag){
  __shared__ int s;
  if (threadIdx.x == 0) s = 0;
  __syncthreads();
  unsigned w = m[threadIdx.x];
  if (w > 1u) atomicOr(&s, 1);
  __syncthreads();
  if (threadIdx.x == 0) *flag = s;   // 1 => byte/bool storage, 0 => int32
}

// mask -> bf16 additive bias in fragment order: biasr[qgrp][jt][lane][16elems]
__global__ __launch_bounds__(256) void mask_bias_kernel(
    const void* __restrict__ mask, const int* __restrict__ flag,
    unsigned short* __restrict__ biasr){
  __shared__ float mt[16][64];
  int qg = blockIdx.x, jt = blockIdx.y;   // qg in [0,64)
  int t = threadIdx.x;
  int fl = *flag;
  int jc = jt*64 + (t&63);
  #pragma unroll
  for (int k2=0;k2<4;k2++){
    int qr = qg*16 + (t>>6) + k2*4;       // qr in [0,1024)
    bool a = fl ? (((const unsigned char*)mask)[(size_t)qr*1024 + jc] != 0)
                : (((const int*)mask)[(size_t)qr*1024 + jc] != 0);
    mt[(t>>6)+k2*4][t&63] = a ? -23.083120654223414f : -1e30f;
  }
  __syncthreads();
  ushort4 ob;
  unsigned short tmp[4];
  #pragma unroll
  for (int u=0;u<4;u++){
    int p = t*4+u;
    int e = p&15, lane = p>>4;
    int i = e>>2, jj = e&3;
    int ln2 = lane&15, g2 = lane>>4;
    tmp[u] = f32_to_bf16(mt[g2*4+i][jj*16+ln2]);
  }
  ob.x=tmp[0]; ob.y=tmp[1]; ob.z=tmp[2]; ob.w=tmp[3];
  *(ushort4*)&biasr[((size_t)(qg*16+jt)*64)*16 + t*4] = ob;
}

// ---------------- weight convert + transpose (float4 vectorized) ------------
__global__ __launch_bounds__(256) void transpose_cvt_kernel(
    const float* __restrict__ W, unsigned short* __restrict__ WT, int K, int N){
  __shared__ float tile[32][37];
  int n0 = blockIdx.x*32, k0 = blockIdx.y*32;
  int r = threadIdx.x>>3, c4 = threadIdx.x&7;
  float4 v = *(const float4*)&W[(size_t)(k0+r)*N + n0 + c4*4];
  tile[r][c4*4+0]=v.x; tile[r][c4*4+1]=v.y; tile[r][c4*4+2]=v.z; tile[r][c4*4+3]=v.w;
  __syncthreads();
  ushort4 o;
  o.x = f32_to_bf16(tile[c4*4+0][r]);
  o.y = f32_to_bf16(tile[c4*4+1][r]);
  o.z = f32_to_bf16(tile[c4*4+2][r]);
  o.w = f32_to_bf16(tile[c4*4+3][r]);
  *(ushort4*)&WT[(size_t)(n0+r)*K + k0 + c4*4] = o;
}

// V slice of qkv [4096][3072] -> VT [b][1024 d][1024 n] bf16
__global__ __launch_bounds__(256) void vtrans_kernel(
    const unsigned short* __restrict__ qkv, unsigned short* __restrict__ vt){
  __shared__ unsigned short t[32][33];
  int b = blockIdx.z;
  int n0 = blockIdx.x*32, d0 = blockIdx.y*32;
  int tx = threadIdx.x & 31, ty = threadIdx.x >> 5;
  #pragma unroll
  for (int r=0;r<4;r++)
    t[ty+8*r][tx] = qkv[(size_t)(b*1024 + n0+ty+8*r)*3072 + 2048 + d0+tx];
  __syncthreads();
  #pragma unroll
  for (int r=0;r<4;r++)
    vt[((size_t)b<<20) + (size_t)(d0+ty+8*r)*1024 + n0+tx] = t[tx][ty+8*r];
}

__global__ void bias_concat_kernel(const float* __restrict__ bq,
                                   const float* __restrict__ bkv,
                                   float* __restrict__ dst){
  int i = blockIdx.x*256 + threadIdx.x;
  if (i < 3072) dst[i] = (i < 1024) ? bq[i] : bkv[i-1024];
}

// ---------------- layernorm (row = 1024 floats) -----------------------------
__global__ __launch_bounds__(256) void ln_kernel(const float* __restrict__ x,
                                                 unsigned short* __restrict__ xn){
  const int C = 1024;
  size_t row = blockIdx.x;
  float4 v = reinterpret_cast<const float4*>(x + row*C)[threadIdx.x];
  float s = v.x+v.y+v.z+v.w;
  float q = v.x*v.x+v.y*v.y+v.z*v.z+v.w*v.w;
  #pragma unroll
  for (int off=32; off; off>>=1){ s += __shfl_xor(s,off); q += __shfl_xor(q,off); }
  __shared__ float sm[8];
  int wv = threadIdx.x>>6, ln = threadIdx.x&63;
  if (ln==0){ sm[wv]=s; sm[4+wv]=q; }
  __syncthreads();
  float S = sm[0]+sm[1]+sm[2]+sm[3];
  float Q = sm[4]+sm[5]+sm[6]+sm[7];
  float mu  = S*(1.0f/1024.0f);
  float var = Q*(1.0f/1024.0f) - mu*mu;
  float inv = rsqrtf(var + 1e-6f);
  ushort4 o;
  o.x = f32_to_bf16((v.x-mu)*inv);
  o.y = f32_to_bf16((v.y-mu)*inv);
  o.z = f32_to_bf16((v.z-mu)*inv);
  o.w = f32_to_bf16((v.w-mu)*inv);
  reinterpret_cast<ushort4*>(xn + row*C)[threadIdx.x] = o;
}

// ---------------- 128x128 4-wave GEMM, templated BK (32 or 64) --------------
// depth-3 counted vmcnt, 2 barriers/step, zero-conflict XOR swizzle.
template<int EPI, int BK>
__global__ __launch_bounds__(256) void gemm128_kernel(
    const unsigned short* __restrict__ A,
    const unsigned short* __restrict__ BT,
    const float* __restrict__ bias,
    const float* __restrict__ resid,
    void* __restrict__ Cout,
    int M, int N, int K)
{
  constexpr int CPR = BK/8;            // 16B chunks per row
  constexpr int PT  = BK/16;           // staged chunks per thread per operand
  constexpr int TS  = 128*BK;          // shorts per operand tile
  __shared__ __align__(16) unsigned short lds[3][2*TS];
  int tid = threadIdx.x, wave = tid>>6, lane = tid&63;
  int nbx = gridDim.x;
  int lin = blockIdx.y*nbx + blockIdx.x;
  int w = xcd_swz(lin, nbx*gridDim.y);
  int m0 = (w/nbx)*128, n0 = (w%nbx)*128;
  int ln = lane&15, g = lane>>4;
  int wm = wave>>1, wn = wave&1;

  const unsigned short* sA[PT];
  const unsigned short* sB[PT];
  #pragma unroll
  for (int p=0;p<PT;p++){
    int idx = p*256 + tid;
    int row = idx/CPR, c = idx%CPR;
    int ch = (BK==32) ? (c ^ ((row>>1)&3)) : (c ^ (row&7));
    sA[p] = A  + (size_t)(m0+row)*K + ch*8;
    sB[p] = BT + (size_t)(n0+row)*K + ch*8;
  }

  f32x4 acc[4][4] = {};
  int nt = K/BK;

  auto STAGE = [&](int t, int buf){
    int ko = t*BK;
    #pragma unroll
    for (int p=0;p<PT;p++)
      gload16(sA[p]+ko, (char*)&lds[buf][0]  + (p*256 + wave*64)*16);
    #pragma unroll
    for (int p=0;p<PT;p++)
      gload16(sB[p]+ko, (char*)&lds[buf][TS] + (p*256 + wave*64)*16);
  };

  STAGE(0,0); STAGE(1,1); STAGE(2,2);

  int cb = 0;
  for (int t=0; t<nt; ++t){
    int rem = nt-1-t;
    if (BK==32){
      if (rem >= 2)      asm volatile("s_waitcnt vmcnt(8)" ::: "memory");
      else if (rem == 1) asm volatile("s_waitcnt vmcnt(4)" ::: "memory");
      else               asm volatile("s_waitcnt vmcnt(0)" ::: "memory");
    } else {
      if (rem >= 2)      asm volatile("s_waitcnt vmcnt(16)" ::: "memory");
      else if (rem == 1) asm volatile("s_waitcnt vmcnt(8)" ::: "memory");
      else               asm volatile("s_waitcnt vmcnt(0)" ::: "memory");
    }
    __builtin_amdgcn_s_barrier();

    const unsigned short* lb = lds[cb];
    #pragma unroll
    for (int kk=0; kk<BK/32; ++kk){
      int swz = (BK==32) ? (g ^ ((ln>>1)&3)) : ((kk*4+g) ^ (ln&7));
      bf16x8 a[4], b[4];
      #pragma unroll
      for (int mi=0;mi<4;mi++)
        a[mi] = *(const bf16x8*)(lb + (wm*64+mi*16+ln)*BK + swz*8);
      #pragma unroll
      for (int ni=0;ni<4;ni++)
        b[ni] = *(const bf16x8*)(lb + TS + (wn*64+ni*16+ln)*BK + swz*8);
      #pragma unroll
      for (int mi=0;mi<4;mi++)
        #pragma unroll
        for (int ni=0;ni<4;ni++)
          acc[mi][ni] = MFMA16(a[mi], b[ni], acc[mi][ni]);
    }

    asm volatile("s_waitcnt lgkmcnt(0)" ::: "memory");
    __builtin_amdgcn_s_barrier();
    if (t+3 < nt) STAGE(t+3, cb);
    cb = (cb==2) ? 0 : cb+1;
  }

  #pragma unroll
  for (int mi=0;mi<4;mi++){
    int r0 = m0 + wm*64 + mi*16 + g*4;
    #pragma unroll
    for (int ni=0;ni<4;ni++){
      int c = n0 + wn*64 + ni*16 + ln;
      float bs = bias[c];
      f32x4 cc = acc[mi][ni];
      #pragma unroll
      for (int i=0;i<4;i++){
        int r = r0 + i;
        float v = cc[i] + bs;
        if (EPI == 1){
          v += resid[(size_t)r*N + c];
          ((float*)Cout)[(size_t)r*N + c] = v;
        } else if (EPI == 2){
          ((unsigned short*)Cout)[(size_t)r*N + c] = f32_to_bf16(gelu_fast(v));
        } else {
          ((unsigned short*)Cout)[(size_t)r*N + c] = f32_to_bf16(v);
        }
      }
    }
  }
}

// ---------------- fused attention: LDS-staged K/V, split-K over keys --------
// (R16/R20 version: QBLK=64, 6 blocks/CU, serial stage per tile — proven best)
__global__ __launch_bounds__(256,6) void attn_kernel(
    const unsigned short* __restrict__ qkv,
    const unsigned short* __restrict__ vt,
    const unsigned short* __restrict__ biasr,
    unsigned short* __restrict__ pn,
    float* __restrict__ lsumg)
{
  const int N = 1024, NK = 3072;
  const float SCL = 0.18033688011112042f;   // 0.125 * log2(e)
  __shared__ __align__(16) unsigned short lK[64*64];
  __shared__ __align__(16) unsigned short lV[64*64];
  __shared__ __align__(16) unsigned short plds[4][16][72];
  int bh = blockIdx.x, qt = blockIdx.y, sp = blockIdx.z;
  int b = bh>>4, h = bh&15;
  int tid = threadIdx.x, wave = tid>>6, lane = tid&63;
  int ln = lane&15, g = lane>>4;
  size_t base = (size_t)b*N;
  int q_local = qt*64 + wave*16;

  const unsigned short* qptr = qkv + (base + q_local + ln)*NK + h*64;
  bf16x8 aq0 = *(const bf16x8*)(qptr + g*8);
  bf16x8 aq1 = *(const bf16x8*)(qptr + 32 + g*8);

  int r0s = tid>>3,        c0 = (tid&7) ^ (r0s&7);
  int r1s = 32 + (tid>>3), c1 = (tid&7) ^ (r1s&7);
  const unsigned short* kg0 = qkv + (base + r0s)*NK + 1024 + h*64 + c0*8;
  const unsigned short* kg1 = qkv + (base + r1s)*NK + 1024 + h*64 + c1*8;
  const unsigned short* vg0 = vt + ((size_t)b<<20) + (size_t)(h*64 + r0s)*N + c0*8;
  const unsigned short* vg1 = vt + ((size_t)b<<20) + (size_t)(h*64 + r1s)*N + c1*8;
  char* lKd0 = (char*)lK + (wave*64)*16;
  char* lKd1 = (char*)lK + (256 + wave*64)*16;
  char* lVd0 = (char*)lV + (wave*64)*16;
  char* lVd1 = (char*)lV + (256 + wave*64)*16;

  const unsigned short* brp = biasr +
      (((size_t)(qt*4 + wave)*16)*64 + lane)*16;

  f32x4 oacc[4] = {};
  float lsum[4] = {0.f,0.f,0.f,0.f};
  const int xl = (ln&7);

  for (int t=0; t<8; ++t){
    int j0 = sp*512 + t*64;
    __syncthreads();
    gload16(kg0 + (size_t)j0*NK, lKd0);
    gload16(kg1 + (size_t)j0*NK, lKd1);
    gload16(vg0 + j0, lVd0);
    gload16(vg1 + j0, lVd1);
    int jt = j0>>6;
    bf16x8 bb0 = *(const bf16x8*)(brp + (size_t)jt*1024);
    bf16x8 bb1 = *(const bf16x8*)(brp + (size_t)jt*1024 + 8);
    asm volatile("s_waitcnt vmcnt(0)" ::: "memory");
    __builtin_amdgcn_s_barrier();

    f32x4 s[4];
    #pragma unroll
    for (int jj=0;jj<4;jj++){
      int row = jj*16+ln;
      bf16x8 k0 = *(const bf16x8*)((const char*)lK + row*128 + ((g^xl)<<4));
      bf16x8 k1 = *(const bf16x8*)((const char*)lK + row*128 + (((g+4)^xl)<<4));
      s[jj] = (f32x4){};
      s[jj] = MFMA16(aq0, k0, s[jj]);
      s[jj] = MFMA16(aq1, k1, s[jj]);
    }
    #pragma unroll
    for (int i=0;i<4;i++){
      #pragma unroll
      for (int jj=0;jj<4;jj++){
        int e = i*4+jj;
        unsigned short bu = (e<8) ? (unsigned short)bb0[e] : (unsigned short)bb1[e-8];
        float ev = exp2f(fmaf(s[jj][i], SCL, bf16_to_f32(bu)));
        lsum[i] += ev;
        plds[wave][4*g+i][jj*16+ln] = f32_to_bf16(ev);
      }
    }
    asm volatile("s_waitcnt lgkmcnt(0)" ::: "memory");
    __builtin_amdgcn_sched_barrier(0);
    bf16x8 p0 = *(const bf16x8*)&plds[wave][ln][g*8];
    bf16x8 p1 = *(const bf16x8*)&plds[wave][ln][32 + g*8];
    #pragma unroll
    for (int nd=0;nd<4;nd++){
      int row = nd*16+ln;
      bf16x8 v0 = *(const bf16x8*)((const char*)lV + row*128 + ((g^xl)<<4));
      bf16x8 v1 = *(const bf16x8*)((const char*)lV + row*128 + (((g+4)^xl)<<4));
      oacc[nd] = MFMA16(p0, v0, oacc[nd]);
      oacc[nd] = MFMA16(p1, v1, oacc[nd]);
    }
  }

  #pragma unroll
  for (int i=0;i<4;i++){
    float l = lsum[i];
    l += __shfl_xor(l,1); l += __shfl_xor(l,2);
    l += __shfl_xor(l,4); l += __shfl_xor(l,8);
    if (ln == 0)
      lsumg[((size_t)sp<<16) + (size_t)(base + q_local + 4*g + i)*16 + h] = l;
  }
  #pragma unroll
  for (int nd=0;nd<4;nd++){
    #pragma unroll
    for (int i=0;i<4;i++){
      int qr = q_local + 4*g + i;
      pn[((size_t)sp<<22) + (base+qr)*1024 + h*64 + nd*16 + ln] = f32_to_bf16(oacc[nd][i]);
    }
  }
}

// combine: o = (pn0+pn1)/(l0+l1), bf16 out.
__global__ __launch_bounds__(256) void attn_reduce_kernel(
    const unsigned short* __restrict__ pn,
    const float* __restrict__ lsumg,
    unsigned short* __restrict__ o)
{
  size_t idx = ((size_t)blockIdx.x*256 + threadIdx.x)*8;
  int r = (int)(idx>>10);
  int h = (int)((idx&1023)>>6);
  float inv = 1.0f/(lsumg[(size_t)r*16+h] + lsumg[(1u<<16) + (size_t)r*16+h]);
  u16x8 p0 = *(const u16x8*)(pn + idx);
  u16x8 p1 = *(const u16x8*)(pn + (1u<<22) + idx);
  u16x8 res;
  #pragma unroll
  for (int e=0;e<8;e++)
    res[e] = f32_to_bf16((bf16_to_f32((unsigned short)p0[e]) +
                          bf16_to_f32((unsigned short)p1[e]))*inv);
  *(u16x8*)(o + idx) = res;
}

// ---------------- host ------------------------------------------------------
extern "C" void kernel_launch(void* const* d_in, const int* in_sizes, int n_in,
                              void* d_out, int out_size, void* d_ws, size_t ws_size,
                              hipStream_t stream)
{
  (void)in_sizes; (void)n_in; (void)out_size; (void)ws_size;
  const float* x   = (const float*)d_in[0];
  const void*  mask= d_in[1];
  const float* wq  = (const float*)d_in[2];
  const float* bq  = (const float*)d_in[3];
  const float* wkv = (const float*)d_in[4];
  const float* bkv = (const float*)d_in[5];
  const float* wo  = (const float*)d_in[6];
  const float* bo  = (const float*)d_in[7];
  const float* w1  = (const float*)d_in[8];
  const float* b1  = (const float*)d_in[9];
  const float* w2  = (const float*)d_in[10];
  const float* b2  = (const float*)d_in[11];
  float* out = (float*)d_out;

  char* ws = (char*)d_ws;
  size_t off = 0;
  auto alloc = [&](size_t bytes){ size_t o = off; off += (bytes + 255) & ~(size_t)255; return o; };
  unsigned short* WqkvT = (unsigned short*)(ws + alloc(3072u*1024u*2));
  unsigned short* WoT   = (unsigned short*)(ws + alloc(1024u*1024u*2));
  unsigned short* W1T   = (unsigned short*)(ws + alloc(4096u*1024u*2));
  unsigned short* W2T   = (unsigned short*)(ws + alloc(1024u*4096u*2));
  float*          BIASQ = (float*)(ws + alloc(3072u*4));
  int*            FLAG  = (int*)(ws + alloc(256));
  float*          LSUM  = (float*)(ws + alloc(2u*4096u*16u*4));
  unsigned short* BIASR = (unsigned short*)(ws + alloc(64u*16u*64u*16u*2)); // 2MB
  unsigned short* XN    = (unsigned short*)(ws + alloc(4096u*1024u*2));
  float*          X1    = (float*)(ws + alloc(4096u*1024u*4));  // PN aliases
  unsigned short* QKV   = (unsigned short*)(ws + alloc(4096u*4096u*2));
  unsigned short* VT    = QKV + (size_t)4096u*3072u;
  unsigned short* PN    = (unsigned short*)X1;

  // prep
  transpose_cvt_kernel<<<dim3(32,32),  256, 0, stream>>>(wq,  WqkvT,               1024, 1024);
  transpose_cvt_kernel<<<dim3(64,32),  256, 0, stream>>>(wkv, WqkvT + 1024u*1024u, 1024, 2048);
  transpose_cvt_kernel<<<dim3(32,32),  256, 0, stream>>>(wo,  WoT,                 1024, 1024);
  transpose_cvt_kernel<<<dim3(128,32), 256, 0, stream>>>(w1,  W1T,                 1024, 4096);
  transpose_cvt_kernel<<<dim3(32,128), 256, 0, stream>>>(w2,  W2T,                 4096, 1024);
  bias_concat_kernel<<<12, 256, 0, stream>>>(bq, bkv, BIASQ);
  detect_mask_kernel<<<1, 256, 0, stream>>>((const unsigned*)mask, FLAG);
  mask_bias_kernel<<<dim3(64,16), 256, 0, stream>>>(mask, FLAG, BIASR);

  // block
  ln_kernel<<<4096, 256, 0, stream>>>(x, XN);
  gemm128_kernel<0,32><<<dim3(24,32), 256, 0, stream>>>(XN, WqkvT, BIASQ, nullptr, QKV, 4096, 3072, 1024);
  vtrans_kernel<<<dim3(32,32,4), 256, 0, stream>>>(QKV, VT);
  attn_kernel<<<dim3(64,16,2), 256, 0, stream>>>(QKV, VT, BIASR, PN, LSUM);
  attn_reduce_kernel<<<2048, 256, 0, stream>>>(PN, LSUM, XN);
  gemm128_kernel<1,64><<<dim3(8,32), 256, 0, stream>>>(XN, WoT, bo, x, X1, 4096, 1024, 1024);
  ln_kernel<<<4096, 256, 0, stream>>>(X1, XN);
  gemm128_kernel<2,32><<<dim3(32,32), 256, 0, stream>>>(XN, W1T, b1, nullptr, QKV, 4096, 4096, 1024);
  gemm128_kernel<1,64><<<dim3(8,32), 256, 0, stream>>>(QKV, W2T, b2, X1, out, 4096, 1024, 4096);
}